// Round 11
// baseline (169.524 us; speedup 1.0000x reference)
//
#include <hip/hip_runtime.h>

// ---------------- problem constants ----------------
#define BATCH 2
#define CH    512
#define NTOK  4096      // H*W
#define NH    8
#define HD    64
#define MTOT  (BATCH*NTOK)   // 8192

typedef __attribute__((ext_vector_type(8))) __bf16 bf16x8;
typedef __attribute__((ext_vector_type(4))) float  f32x4;
typedef __attribute__((ext_vector_type(4))) unsigned short u16x4;

static __device__ __forceinline__ f32x4 mfma16(bf16x8 a, bf16x8 b, f32x4 c) {
  return __builtin_amdgcn_mfma_f32_16x16x32_bf16(a, b, c, 0, 0, 0);
}

static __device__ __forceinline__ unsigned short f2bf(float f) {
  unsigned int u = __float_as_uint(f);
  u += 0x7fffu + ((u >> 16) & 1u);
  return (unsigned short)(u >> 16);
}

static __device__ __forceinline__ void gload_lds16(const unsigned short* g, unsigned short* l) {
  __builtin_amdgcn_global_load_lds((const __attribute__((address_space(1))) void*)g,
                                   (__attribute__((address_space(3))) void*)l, 16, 0, 0);
}

// q pre-scale: (1/sqrt(HD)) * log2(e)  -> QK^T lands directly in exp2 domain
#define QSC 0.18033688011112042f

// ---------------- kernel 1: x [B,C,N] -> tokens [B,N,C] bf16 ----------------
__global__ __launch_bounds__(256) void k_transpose(const float* __restrict__ x,
                                                   unsigned short* __restrict__ tokB) {
  __shared__ float tile[32][33];
  int b  = blockIdx.z;
  int n0 = blockIdx.x * 32;
  int c0 = blockIdx.y * 32;
  int tx = threadIdx.x & 31, ty = threadIdx.x >> 5;  // 32 x 8
#pragma unroll
  for (int i = 0; i < 4; i++) {
    int c = c0 + ty + 8 * i;
    tile[ty + 8 * i][tx] = x[((size_t)b * CH + c) * NTOK + n0 + tx];
  }
  __syncthreads();
#pragma unroll
  for (int i = 0; i < 4; i++) {
    int n = n0 + ty + 8 * i;
    int c = c0 + tx;
    tokB[((size_t)b * NTOK + n) * CH + c] = f2bf(tile[tx][ty + 8 * i]);
  }
}

// ---------------- kernel 2: both weight casts in one launch ----------------
__global__ __launch_bounds__(256) void k_castw(const float* __restrict__ w1,
                                               const float* __restrict__ w2,
                                               unsigned short* __restrict__ o1,
                                               unsigned short* __restrict__ o2) {
  int i = blockIdx.x * 256 + threadIdx.x;
  if (i < 3 * CH * CH) o1[i] = f2bf(w1[i]);
  else o2[i - 3 * CH * CH] = f2bf(w2[i - 3 * CH * CH]);
}

// ---------------- GEMM helpers ----------------
#define BK 64

// async-stage one 128x64 bf16 tile into swizzled LDS via global_load_lds.
static __device__ __forceinline__ void stage_g(const unsigned short* __restrict__ src,
                                               size_t row0, int k0,
                                               unsigned short* __restrict__ lds,
                                               int wid, int lane) {
  int sub = lane >> 3;               // 0..7 : row within 8-row group
  int ch  = (lane & 7) ^ sub;        // pre-swizzled source chunk
#pragma unroll
  for (int i = 0; i < 4; i++) {
    int rbase = 32 * wid + 8 * i;
    gload_lds16(&src[(row0 + rbase + sub) * 512 + k0 + ch * 8], &lds[rbase * BK]);
  }
}

// 64-row variant
static __device__ __forceinline__ void stage_g64(const unsigned short* __restrict__ src,
                                                 size_t row0, int k0,
                                                 unsigned short* __restrict__ lds,
                                                 int wid, int lane) {
  int sub = lane >> 3;
  int ch  = (lane & 7) ^ sub;
#pragma unroll
  for (int i = 0; i < 2; i++) {
    int rbase = 16 * wid + 8 * i;
    gload_lds16(&src[(row0 + rbase + sub) * 512 + k0 + ch * 8], &lds[rbase * BK]);
  }
}

static __device__ __forceinline__ bf16x8 frag_ld(const unsigned short* __restrict__ lds,
                                                 int row, int ks, int lane) {
  int ch = ((ks << 2) + (lane >> 4)) ^ (row & 7);
  return *reinterpret_cast<const bf16x8*>(&lds[row * BK + ch * 8]);
}

// ---------------- kernel 3: QKV GEMM -> q(pre-scaled)/k [B,H,N,D], V^T [B,H,D,N] ----------------
__global__ __launch_bounds__(256) void k_gemm_qkv(const unsigned short* __restrict__ A,
                                                  const unsigned short* __restrict__ W,
                                                  const float* __restrict__ bias,
                                                  unsigned short* __restrict__ qb,
                                                  unsigned short* __restrict__ kb,
                                                  unsigned short* __restrict__ vt) {
  __shared__ unsigned short lsA[128 * BK];
  __shared__ unsigned short lsB[128 * BK];
  int bm0 = blockIdx.x * 128;
  int bn0 = blockIdx.y * 128;
  int tid = threadIdx.x, lane = tid & 63, wid = tid >> 6;
  int wm = wid >> 1, wn = wid & 1;

  f32x4 acc[4][4];
  f32x4 zz = {0.f, 0.f, 0.f, 0.f};
#pragma unroll
  for (int i = 0; i < 4; i++)
#pragma unroll
    for (int j = 0; j < 4; j++) acc[i][j] = zz;

  for (int k0 = 0; k0 < 512; k0 += BK) {
    stage_g(A, (size_t)bm0, k0, lsA, wid, lane);
    stage_g(W, (size_t)bn0, k0, lsB, wid, lane);
    __syncthreads();
#pragma unroll
    for (int ks = 0; ks < 2; ks++) {
      bf16x8 af[4], bfr[4];
#pragma unroll
      for (int t = 0; t < 4; t++) {
        af[t]  = frag_ld(lsA, wm * 64 + t * 16 + (lane & 15), ks, lane);
        bfr[t] = frag_ld(lsB, wn * 64 + t * 16 + (lane & 15), ks, lane);
      }
#pragma unroll
      for (int mt = 0; mt < 4; mt++)
#pragma unroll
        for (int nt = 0; nt < 4; nt++) acc[mt][nt] = mfma16(af[mt], bfr[nt], acc[mt][nt]);
    }
    __syncthreads();
  }
#pragma unroll
  for (int nt = 0; nt < 4; nt++) {
    int j = bn0 + wn * 64 + nt * 16 + (lane & 15);
    float bj = bias[j];
    int which = j >> 9;        // wave-uniform
    int cp = j & 511;
    int h = cp >> 6, d = cp & 63;
    if (which == 2) {
#pragma unroll
      for (int mt = 0; mt < 4; mt++) {
        int m = bm0 + wm * 64 + mt * 16 + 4 * (lane >> 4);
        int b = m >> 12, n = m & 4095;
        u16x4 pk;
#pragma unroll
        for (int r = 0; r < 4; r++) pk[r] = f2bf(acc[mt][nt][r] + bj);
        *reinterpret_cast<u16x4*>(&vt[((size_t)((b * NH + h) * HD + d)) * NTOK + n]) = pk;
      }
    } else {
      unsigned short* dst = (which == 0) ? qb : kb;
      float sc = (which == 0) ? QSC : 1.0f;
#pragma unroll
      for (int mt = 0; mt < 4; mt++) {
#pragma unroll
        for (int r = 0; r < 4; r++) {
          int m = bm0 + wm * 64 + mt * 16 + 4 * (lane >> 4) + r;
          int b = m >> 12, n = m & 4095;
          dst[(((size_t)(b * NH + h) * NTOK + n) << 6) + d] = f2bf((acc[mt][nt][r] + bj) * sc);
        }
      }
    }
  }
}

// ---------------- kernel 4: flash attention ----------------
// 16 q/wave, 64 q/block, 1024 blocks (4/CU, 4 waves/SIMD); sigma-reordered QK^T:
// PV A-fragment assembles in-register from cvt_pk words (no P-LDS round-trip);
// K/V LDS dbuf 32KB; no-max softmax (exp2 domain via q pre-scale); l via
// ones-MFMA; bijective XCD swizzle (2 bh per XCD -> K/V L2-resident).
#define KVB 64
#define NT  (NTOK / KVB)   // 64

static __device__ __forceinline__ void stage_kv(const unsigned short* __restrict__ Kp,
                                                const unsigned short* __restrict__ Vp,
                                                unsigned short* __restrict__ lk,
                                                unsigned short* __restrict__ lv,
                                                int kv0, int wid, int lane) {
  int sub = lane >> 3;        // row within 8-row group
  int c7  = lane & 7;         // dest chunk
#pragma unroll
  for (int i = 0; i < 2; i++) {
    int rbase = 16 * wid + 8 * i;
    int row = rbase + sub;
    int fk = (sub & 3) | (i << 2);          // f(row) for K (sigma key)
    gload_lds16(&Kp[((size_t)(kv0 + row) << 6) + ((c7 ^ fk) << 3)], &lk[rbase << 6]);
    gload_lds16(&Vp[(size_t)row * NTOK + kv0 + ((c7 ^ sub) << 3)], &lv[rbase << 6]);
  }
}

static __device__ __forceinline__ void attn_tile(const unsigned short* __restrict__ lk,
                                                 const unsigned short* __restrict__ lv,
                                                 const bf16x8 qf[2],
                                                 f32x4* oacc, f32x4& lacc,
                                                 bf16x8 onesf, int g, int lr) {
  f32x4 zz = {0.f, 0.f, 0.f, 0.f};
  int l7 = lr & 7;
  int tbase = 8 * (lr >> 2) + (lr & 3);
  int kc0 = ((g ^ l7) << 3);
  int kc1 = (((4 + g) ^ l7) << 3);
  // K fragments (sigma row order)
  bf16x8 kf[4][2];
#pragma unroll
  for (int ct = 0; ct < 4; ct++) {
    int t = tbase + 4 * (ct >> 1) + 32 * (ct & 1);
    kf[ct][0] = *reinterpret_cast<const bf16x8*>(&lk[(t << 6) + kc0]);
    kf[ct][1] = *reinterpret_cast<const bf16x8*>(&lk[(t << 6) + kc1]);
  }
  f32x4 s[4];
#pragma unroll
  for (int ct = 0; ct < 4; ct++) {
    s[ct] = mfma16(kf[ct][0], qf[0], zz);
    s[ct] = mfma16(kf[ct][1], qf[1], s[ct]);
  }
  // V fragments (natural order; issue early, latency hides under softmax)
  bf16x8 vf[4][2];
#pragma unroll
  for (int dt = 0; dt < 4; dt++) {
    int rowb = (dt * 16 + lr) << 6;
    vf[dt][0] = *reinterpret_cast<const bf16x8*>(&lv[rowb + kc0]);
    vf[dt][1] = *reinterpret_cast<const bf16x8*>(&lv[rowb + kc1]);
  }
  // softmax: exp2 then pack straight into PV A-fragments (in-register)
#pragma unroll
  for (int ct = 0; ct < 4; ct++) {
#pragma unroll
    for (int r = 0; r < 4; r++) s[ct][r] = __builtin_exp2f(s[ct][r]);
  }
  unsigned int w[4][2];
#pragma unroll
  for (int ct = 0; ct < 4; ct++) {
    asm("v_cvt_pk_bf16_f32 %0, %1, %2" : "=v"(w[ct][0]) : "v"(s[ct][0]), "v"(s[ct][1]));
    asm("v_cvt_pk_bf16_f32 %0, %1, %2" : "=v"(w[ct][1]) : "v"(s[ct][2]), "v"(s[ct][3]));
  }
  union U { unsigned int w[4]; bf16x8 v; };
  U a0, a1;
  a0.w[0] = w[0][0]; a0.w[1] = w[0][1]; a0.w[2] = w[2][0]; a0.w[3] = w[2][1]; // k=8g..8g+7
  a1.w[0] = w[1][0]; a1.w[1] = w[1][1]; a1.w[2] = w[3][0]; a1.w[3] = w[3][1]; // k=32+8g..
#pragma unroll
  for (int dt = 0; dt < 4; dt++) {
    oacc[dt] = mfma16(a0.v, vf[dt][0], oacc[dt]);
    oacc[dt] = mfma16(a1.v, vf[dt][1], oacc[dt]);
  }
  lacc = mfma16(a0.v, onesf, lacc);
  lacc = mfma16(a1.v, onesf, lacc);
}

__global__ __launch_bounds__(256, 4) void k_attn(const unsigned short* __restrict__ Q,
                                                 const unsigned short* __restrict__ K,
                                                 const unsigned short* __restrict__ Vt,
                                                 unsigned short* __restrict__ O) {
  __shared__ unsigned short lsK[2][KVB * 64];      // 8KB each
  __shared__ unsigned short lsV[2][64 * KVB];      // 8KB each
  // bijective XCD swizzle: 128 consecutive vv (= 2 bh) per XCD
  int gid = blockIdx.x;                            // 1024 blocks
  int vv  = (gid & 7) * 128 + (gid >> 3);
  int bh  = vv >> 6;
  int tid = threadIdx.x, lane = tid & 63, wid = tid >> 6;
  int g = lane >> 4, lr = lane & 15;
  int qw = (vv & 63) * 64 + wid * 16;
  const unsigned short* Qp = Q + (size_t)bh * NTOK * HD;
  const unsigned short* Kp = K + (size_t)bh * NTOK * HD;
  const unsigned short* Vp = Vt + (size_t)bh * HD * NTOK;
  unsigned short* K0 = &lsK[0][0]; unsigned short* K1 = &lsK[1][0];
  unsigned short* V0 = &lsV[0][0]; unsigned short* V1 = &lsV[1][0];

  union { unsigned short u[8]; bf16x8 v; } ou;
#pragma unroll
  for (int i = 0; i < 8; i++) ou.u[i] = 0x3F80;   // bf16 1.0
  bf16x8 onesf = ou.v;

  bf16x8 qf[2];
#pragma unroll
  for (int ks = 0; ks < 2; ks++)
    qf[ks] = *reinterpret_cast<const bf16x8*>(
        &Qp[(size_t)(qw + lr) * HD + ks * 32 + 8 * g]);

  f32x4 zz = {0.f, 0.f, 0.f, 0.f};
  f32x4 oacc[4] = {zz, zz, zz, zz};
  f32x4 lacc = zz;

  stage_kv(Kp, Vp, K0, V0, 0, wid, lane);
  __syncthreads();

  for (int t = 0; t < NT; t += 2) {
    stage_kv(Kp, Vp, K1, V1, (t + 1) * KVB, wid, lane);
    attn_tile(K0, V0, qf, oacc, lacc, onesf, g, lr);
    __syncthreads();
    if (t + 2 < NT) stage_kv(Kp, Vp, K0, V0, (t + 2) * KVB, wid, lane);
    attn_tile(K1, V1, qf, oacc, lacc, onesf, g, lr);
    __syncthreads();
  }
  // finalize: lacc[r] = l for row q=4g+r (replicated over lr) -> no shuffles
  int b2 = bh >> 3, h = bh & 7;
#pragma unroll
  for (int r = 0; r < 4; r++) {
    float inv = 1.0f / lacc[r];
    int n = qw + 4 * g + r;
#pragma unroll
    for (int dt = 0; dt < 4; dt++) {
      int d = dt * 16 + lr;
      O[((size_t)(b2 * NTOK + n)) * CH + h * HD + d] = f2bf(oacc[dt][r] * inv);
    }
  }
}

// ---------------- kernel 5: out-proj GEMM + bias + residual -> res bf16 ----------------
// BM=64 (512 blocks, 2/CU), BN=128
__global__ __launch_bounds__(256) void k_gemm_out(const unsigned short* __restrict__ A,
                                                  const unsigned short* __restrict__ W,
                                                  const float* __restrict__ bias,
                                                  const unsigned short* __restrict__ tokB,
                                                  unsigned short* __restrict__ res) {
  __shared__ unsigned short lsA[64 * BK];
  __shared__ unsigned short lsB[128 * BK];
  int bm0 = blockIdx.x * 64;
  int bn0 = blockIdx.y * 128;
  int tid = threadIdx.x, lane = tid & 63, wid = tid >> 6;
  int wm = wid >> 1, wn = wid & 1;

  f32x4 acc[2][4];
  f32x4 zz = {0.f, 0.f, 0.f, 0.f};
#pragma unroll
  for (int i = 0; i < 2; i++)
#pragma unroll
    for (int j = 0; j < 4; j++) acc[i][j] = zz;

  for (int k0 = 0; k0 < 512; k0 += BK) {
    stage_g64(A, (size_t)bm0, k0, lsA, wid, lane);
    stage_g(W, (size_t)bn0, k0, lsB, wid, lane);
    __syncthreads();
#pragma unroll
    for (int ks = 0; ks < 2; ks++) {
      bf16x8 af[2], bfr[4];
#pragma unroll
      for (int t = 0; t < 2; t++)
        af[t] = frag_ld(lsA, wm * 32 + t * 16 + (lane & 15), ks, lane);
#pragma unroll
      for (int t = 0; t < 4; t++)
        bfr[t] = frag_ld(lsB, wn * 64 + t * 16 + (lane & 15), ks, lane);
#pragma unroll
      for (int mt = 0; mt < 2; mt++)
#pragma unroll
        for (int nt = 0; nt < 4; nt++) acc[mt][nt] = mfma16(af[mt], bfr[nt], acc[mt][nt]);
    }
    __syncthreads();
  }
#pragma unroll
  for (int nt = 0; nt < 4; nt++) {
    int j = bn0 + wn * 64 + nt * 16 + (lane & 15);
    float bj = bias[j];
#pragma unroll
    for (int mt = 0; mt < 2; mt++) {
#pragma unroll
      for (int r = 0; r < 4; r++) {
        int m = bm0 + wm * 32 + mt * 16 + 4 * (lane >> 4) + r;
        size_t idx = (size_t)m * CH + j;
        float tk = __uint_as_float((unsigned int)tokB[idx] << 16);
        res[idx] = f2bf(acc[mt][nt][r] + bj + tk);
      }
    }
  }
}

// ---------------- kernel 6: LayerNorm over C (bf16 res) + transposed write ----------------
__global__ __launch_bounds__(256) void k_ln(const unsigned short* __restrict__ res,
                                            const float* __restrict__ g,
                                            const float* __restrict__ bb,
                                            float* __restrict__ y) {
  __shared__ float smean[64], srstd[64];
  int m0 = blockIdx.x * 64;
  int tid = threadIdx.x, lane = tid & 63, wid = tid >> 6;
  for (int t = 0; t < 16; t++) {
    int idx = wid * 16 + t;
    uint4 v = *reinterpret_cast<const uint4*>(&res[(size_t)(m0 + idx) * CH + lane * 8]);
    unsigned int wv[4] = {v.x, v.y, v.z, v.w};
    float s = 0.f, ss = 0.f;
#pragma unroll
    for (int j = 0; j < 4; j++) {
      float lo = __uint_as_float(wv[j] << 16);
      float hi = __uint_as_float(wv[j] & 0xFFFF0000u);
      s += lo + hi; ss += lo * lo + hi * hi;
    }
#pragma unroll
    for (int off = 1; off < 64; off <<= 1) {
      s += __shfl_xor(s, off);
      ss += __shfl_xor(ss, off);
    }
    if (lane == 0) {
      float mean = s * (1.0f / CH);
      float var = ss * (1.0f / CH) - mean * mean;
      smean[idx] = mean;
      srstd[idx] = rsqrtf(var + 1e-5f);
    }
  }
  __syncthreads();
  int b = m0 >> 12, n0 = m0 & 4095;
  int tn = tid & 63;
  int cq = tid >> 6;
  float mn = smean[tn], rs = srstd[tn];
  const unsigned short* rrow = res + (size_t)(m0 + tn) * CH;
  float* yb = y + ((size_t)b * CH) * NTOK + n0 + tn;
#pragma unroll
  for (int i = 0; i < 16; i++) {
    int c = cq * 128 + i * 8;
    uint4 v = *reinterpret_cast<const uint4*>(&rrow[c]);
    unsigned int wv[4] = {v.x, v.y, v.z, v.w};
    float4 ga = *reinterpret_cast<const float4*>(&g[c]);
    float4 gb = *reinterpret_cast<const float4*>(&g[c + 4]);
    float4 ba = *reinterpret_cast<const float4*>(&bb[c]);
    float4 b4 = *reinterpret_cast<const float4*>(&bb[c + 4]);
    float gg[8] = {ga.x, ga.y, ga.z, ga.w, gb.x, gb.y, gb.z, gb.w};
    float bv[8] = {ba.x, ba.y, ba.z, ba.w, b4.x, b4.y, b4.z, b4.w};
#pragma unroll
    for (int j = 0; j < 4; j++) {
      float lo = __uint_as_float(wv[j] << 16);
      float hi = __uint_as_float(wv[j] & 0xFFFF0000u);
      yb[(size_t)(c + 2 * j) * NTOK]     = (lo - mn) * rs * gg[2 * j]     + bv[2 * j];
      yb[(size_t)(c + 2 * j + 1) * NTOK] = (hi - mn) * rs * gg[2 * j + 1] + bv[2 * j + 1];
    }
  }
}

// ---------------- launch ----------------
extern "C" void kernel_launch(void* const* d_in, const int* in_sizes, int n_in,
                              void* d_out, int out_size, void* d_ws, size_t ws_size,
                              hipStream_t stream) {
  const float* x    = (const float*)d_in[0];
  const float* qkvw = (const float*)d_in[1];
  const float* qkvb = (const float*)d_in[2];
  const float* outw = (const float*)d_in[3];
  const float* outb = (const float*)d_in[4];
  const float* lng  = (const float*)d_in[5];
  const float* lnb  = (const float*)d_in[6];
  float* y = (float*)d_out;

  const size_t NC = (size_t)MTOT * CH;   // 4.2M elements
  char* ws = (char*)d_ws;
  size_t off = 0;
  auto nxt = [&](size_t bytes) -> void* {
    void* p = ws + off;
    off += (bytes + 255) & ~(size_t)255;
    return p;
  };
  unsigned short* tokB = (unsigned short*)nxt(NC * 2);
  unsigned short* wqkv = (unsigned short*)nxt((size_t)3 * CH * CH * 2);
  unsigned short* wout = (unsigned short*)nxt((size_t)CH * CH * 2);
  unsigned short* qb   = (unsigned short*)nxt(NC * 2);
  unsigned short* kb   = (unsigned short*)nxt(NC * 2);
  unsigned short* vt   = (unsigned short*)nxt(NC * 2);
  unsigned short* ao   = (unsigned short*)nxt(NC * 2);
  unsigned short* resb = (unsigned short*)nxt(NC * 2);
  if (off > ws_size) return;

  k_transpose<<<dim3(NTOK / 32, CH / 32, BATCH), 256, 0, stream>>>(x, tokB);
  k_castw<<<(4 * CH * CH) / 256, 256, 0, stream>>>(qkvw, outw, wqkv, wout);
  k_gemm_qkv<<<dim3(MTOT / 128, (3 * CH) / 128), 256, 0, stream>>>(tokB, wqkv, qkvb, qb, kb, vt);
  k_attn<<<1024, 256, 0, stream>>>(qb, kb, vt, ao);
  k_gemm_out<<<dim3(MTOT / 64, CH / 128), 256, 0, stream>>>(ao, wout, outb, tokB, resb);
  k_ln<<<MTOT / 64, 256, 0, stream>>>(resb, lng, lnb, y);
}

// Round 12
// 167.194 us; speedup vs baseline: 1.0139x; 1.0139x over previous
//
#include <hip/hip_runtime.h>

// ---------------- problem constants ----------------
#define BATCH 2
#define CH    512
#define NTOK  4096      // H*W
#define NH    8
#define HD    64
#define MTOT  (BATCH*NTOK)   // 8192

typedef __attribute__((ext_vector_type(8))) __bf16 bf16x8;
typedef __attribute__((ext_vector_type(4))) float  f32x4;
typedef __attribute__((ext_vector_type(4))) unsigned short u16x4;

static __device__ __forceinline__ f32x4 mfma16(bf16x8 a, bf16x8 b, f32x4 c) {
  return __builtin_amdgcn_mfma_f32_16x16x32_bf16(a, b, c, 0, 0, 0);
}

static __device__ __forceinline__ unsigned short f2bf(float f) {
  unsigned int u = __float_as_uint(f);
  u += 0x7fffu + ((u >> 16) & 1u);
  return (unsigned short)(u >> 16);
}

static __device__ __forceinline__ void gload_lds16(const unsigned short* g, unsigned short* l) {
  __builtin_amdgcn_global_load_lds((const __attribute__((address_space(1))) void*)g,
                                   (__attribute__((address_space(3))) void*)l, 16, 0, 0);
}

// q pre-scale: (1/sqrt(HD)) * log2(e)  -> QK^T lands directly in exp2 domain
#define QSC 0.18033688011112042f

// ---------------- kernel 1: x [B,C,N] -> tokens [B,N,C] bf16 ----------------
__global__ __launch_bounds__(256) void k_transpose(const float* __restrict__ x,
                                                   unsigned short* __restrict__ tokB) {
  __shared__ float tile[32][33];
  int b  = blockIdx.z;
  int n0 = blockIdx.x * 32;
  int c0 = blockIdx.y * 32;
  int tx = threadIdx.x & 31, ty = threadIdx.x >> 5;  // 32 x 8
#pragma unroll
  for (int i = 0; i < 4; i++) {
    int c = c0 + ty + 8 * i;
    tile[ty + 8 * i][tx] = x[((size_t)b * CH + c) * NTOK + n0 + tx];
  }
  __syncthreads();
#pragma unroll
  for (int i = 0; i < 4; i++) {
    int n = n0 + ty + 8 * i;
    int c = c0 + tx;
    tokB[((size_t)b * NTOK + n) * CH + c] = f2bf(tile[tx][ty + 8 * i]);
  }
}

// ---------------- kernel 2: both weight casts in one launch ----------------
__global__ __launch_bounds__(256) void k_castw(const float* __restrict__ w1,
                                               const float* __restrict__ w2,
                                               unsigned short* __restrict__ o1,
                                               unsigned short* __restrict__ o2) {
  int i = blockIdx.x * 256 + threadIdx.x;
  if (i < 3 * CH * CH) o1[i] = f2bf(w1[i]);
  else o2[i - 3 * CH * CH] = f2bf(w2[i - 3 * CH * CH]);
}

// ---------------- GEMM helpers ----------------
#define BK 64

// async-stage one 128x64 bf16 tile into swizzled LDS via global_load_lds.
static __device__ __forceinline__ void stage_g(const unsigned short* __restrict__ src,
                                               size_t row0, int k0,
                                               unsigned short* __restrict__ lds,
                                               int wid, int lane) {
  int sub = lane >> 3;               // 0..7 : row within 8-row group
  int ch  = (lane & 7) ^ sub;        // pre-swizzled source chunk
#pragma unroll
  for (int i = 0; i < 4; i++) {
    int rbase = 32 * wid + 8 * i;
    gload_lds16(&src[(row0 + rbase + sub) * 512 + k0 + ch * 8], &lds[rbase * BK]);
  }
}

// 64-row variant
static __device__ __forceinline__ void stage_g64(const unsigned short* __restrict__ src,
                                                 size_t row0, int k0,
                                                 unsigned short* __restrict__ lds,
                                                 int wid, int lane) {
  int sub = lane >> 3;
  int ch  = (lane & 7) ^ sub;
#pragma unroll
  for (int i = 0; i < 2; i++) {
    int rbase = 16 * wid + 8 * i;
    gload_lds16(&src[(row0 + rbase + sub) * 512 + k0 + ch * 8], &lds[rbase * BK]);
  }
}

static __device__ __forceinline__ bf16x8 frag_ld(const unsigned short* __restrict__ lds,
                                                 int row, int ks, int lane) {
  int ch = ((ks << 2) + (lane >> 4)) ^ (row & 7);
  return *reinterpret_cast<const bf16x8*>(&lds[row * BK + ch * 8]);
}

// ---------------- kernel 3: QKV GEMM -> q(pre-scaled)/k [B,H,N,D], V^T [B,H,D,N] ----------------
__global__ __launch_bounds__(256) void k_gemm_qkv(const unsigned short* __restrict__ A,
                                                  const unsigned short* __restrict__ W,
                                                  const float* __restrict__ bias,
                                                  unsigned short* __restrict__ qb,
                                                  unsigned short* __restrict__ kb,
                                                  unsigned short* __restrict__ vt) {
  __shared__ unsigned short lsA[128 * BK];
  __shared__ unsigned short lsB[128 * BK];
  int bm0 = blockIdx.x * 128;
  int bn0 = blockIdx.y * 128;
  int tid = threadIdx.x, lane = tid & 63, wid = tid >> 6;
  int wm = wid >> 1, wn = wid & 1;

  f32x4 acc[4][4];
  f32x4 zz = {0.f, 0.f, 0.f, 0.f};
#pragma unroll
  for (int i = 0; i < 4; i++)
#pragma unroll
    for (int j = 0; j < 4; j++) acc[i][j] = zz;

  for (int k0 = 0; k0 < 512; k0 += BK) {
    stage_g(A, (size_t)bm0, k0, lsA, wid, lane);
    stage_g(W, (size_t)bn0, k0, lsB, wid, lane);
    __syncthreads();
#pragma unroll
    for (int ks = 0; ks < 2; ks++) {
      bf16x8 af[4], bfr[4];
#pragma unroll
      for (int t = 0; t < 4; t++) {
        af[t]  = frag_ld(lsA, wm * 64 + t * 16 + (lane & 15), ks, lane);
        bfr[t] = frag_ld(lsB, wn * 64 + t * 16 + (lane & 15), ks, lane);
      }
#pragma unroll
      for (int mt = 0; mt < 4; mt++)
#pragma unroll
        for (int nt = 0; nt < 4; nt++) acc[mt][nt] = mfma16(af[mt], bfr[nt], acc[mt][nt]);
    }
    __syncthreads();
  }
#pragma unroll
  for (int nt = 0; nt < 4; nt++) {
    int j = bn0 + wn * 64 + nt * 16 + (lane & 15);
    float bj = bias[j];
    int which = j >> 9;        // wave-uniform
    int cp = j & 511;
    int h = cp >> 6, d = cp & 63;
    if (which == 2) {
#pragma unroll
      for (int mt = 0; mt < 4; mt++) {
        int m = bm0 + wm * 64 + mt * 16 + 4 * (lane >> 4);
        int b = m >> 12, n = m & 4095;
        u16x4 pk;
#pragma unroll
        for (int r = 0; r < 4; r++) pk[r] = f2bf(acc[mt][nt][r] + bj);
        *reinterpret_cast<u16x4*>(&vt[((size_t)((b * NH + h) * HD + d)) * NTOK + n]) = pk;
      }
    } else {
      unsigned short* dst = (which == 0) ? qb : kb;
      float sc = (which == 0) ? QSC : 1.0f;
#pragma unroll
      for (int mt = 0; mt < 4; mt++) {
#pragma unroll
        for (int r = 0; r < 4; r++) {
          int m = bm0 + wm * 64 + mt * 16 + 4 * (lane >> 4) + r;
          int b = m >> 12, n = m & 4095;
          dst[(((size_t)(b * NH + h) * NTOK + n) << 6) + d] = f2bf((acc[mt][nt][r] + bj) * sc);
        }
      }
    }
  }
}

// ---------------- kernel 4: flash attention ----------------
// Block = 4 waves, 64 q/block, 1024 blocks (4/CU). Wave w: q-pair (w>>1, 32 q)
// x kv-half (w&1, 32 of each 64-token staged tile). Shared tile stream (32KB
// dbuf). sigma in-register P (no P-LDS round-trip); no-max softmax (exp2 via q
// pre-scale); l via ones-MFMA; kv-half partials additive -> in-block LDS merge.
#define KVB 64
#define NT  (NTOK / KVB)   // 64

static __device__ __forceinline__ void stage_kv(const unsigned short* __restrict__ Kp,
                                                const unsigned short* __restrict__ Vp,
                                                unsigned short* __restrict__ lk,
                                                unsigned short* __restrict__ lv,
                                                int kv0, int wid, int lane) {
  int sub = lane >> 3;        // row within 8-row group
  int c7  = lane & 7;         // dest chunk
#pragma unroll
  for (int i = 0; i < 2; i++) {
    int rbase = 16 * wid + 8 * i;
    int row = rbase + sub;
    int fk = (sub & 3) | (i << 2);          // f(row) for K (sigma key)
    gload_lds16(&Kp[((size_t)(kv0 + row) << 6) + ((c7 ^ fk) << 3)], &lk[rbase << 6]);
    gload_lds16(&Vp[(size_t)row * NTOK + kv0 + ((c7 ^ sub) << 3)], &lv[rbase << 6]);
  }
}

static __device__ __forceinline__ void attn_tile(const unsigned short* __restrict__ lk,
                                                 const unsigned short* __restrict__ lv,
                                                 int half,
                                                 const bf16x8 qf[2][2],
                                                 f32x4* oacc0, f32x4* oacc1,
                                                 f32x4& lacc0, f32x4& lacc1,
                                                 bf16x8 onesf, int g, int lr) {
  f32x4 zz = {0.f, 0.f, 0.f, 0.f};
  int l7 = lr & 7;
  int tbase = 32 * half + 8 * (lr >> 2) + (lr & 3);
  int kc0 = (g ^ l7) << 3;
  int kc1 = ((4 + g) ^ l7) << 3;
  // K fragments (sigma row order), kv-half of the tile
  bf16x8 kf[2][2];
#pragma unroll
  for (int ct = 0; ct < 2; ct++) {
    int t = tbase + 4 * ct;
    kf[ct][0] = *reinterpret_cast<const bf16x8*>(&lk[(t << 6) + kc0]);
    kf[ct][1] = *reinterpret_cast<const bf16x8*>(&lk[(t << 6) + kc1]);
  }
  f32x4 s0[2], s1[2];
#pragma unroll
  for (int ct = 0; ct < 2; ct++) {
    s0[ct] = mfma16(kf[ct][0], qf[0][0], zz);
    s0[ct] = mfma16(kf[ct][1], qf[0][1], s0[ct]);
    s1[ct] = mfma16(kf[ct][0], qf[1][0], zz);
    s1[ct] = mfma16(kf[ct][1], qf[1][1], s1[ct]);
  }
  // V fragments for this kv-half (issue early; hides under softmax)
  bf16x8 vf[4];
  int vc = (((half << 2) + g) ^ l7) << 3;
#pragma unroll
  for (int dt = 0; dt < 4; dt++)
    vf[dt] = *reinterpret_cast<const bf16x8*>(&lv[((dt * 16 + lr) << 6) + vc]);
  // softmax: exp2 then pack straight into PV A-fragments (in-register)
#pragma unroll
  for (int ct = 0; ct < 2; ct++) {
#pragma unroll
    for (int r = 0; r < 4; r++) {
      s0[ct][r] = __builtin_exp2f(s0[ct][r]);
      s1[ct][r] = __builtin_exp2f(s1[ct][r]);
    }
  }
  unsigned int w0[2][2], w1[2][2];
#pragma unroll
  for (int ct = 0; ct < 2; ct++) {
    asm("v_cvt_pk_bf16_f32 %0, %1, %2" : "=v"(w0[ct][0]) : "v"(s0[ct][0]), "v"(s0[ct][1]));
    asm("v_cvt_pk_bf16_f32 %0, %1, %2" : "=v"(w0[ct][1]) : "v"(s0[ct][2]), "v"(s0[ct][3]));
    asm("v_cvt_pk_bf16_f32 %0, %1, %2" : "=v"(w1[ct][0]) : "v"(s1[ct][0]), "v"(s1[ct][1]));
    asm("v_cvt_pk_bf16_f32 %0, %1, %2" : "=v"(w1[ct][1]) : "v"(s1[ct][2]), "v"(s1[ct][3]));
  }
  union U { unsigned int w[4]; bf16x8 v; };
  U a0, b0;
  a0.w[0] = w0[0][0]; a0.w[1] = w0[0][1]; a0.w[2] = w0[1][0]; a0.w[3] = w0[1][1]; // k=8g..8g+7
  b0.w[0] = w1[0][0]; b0.w[1] = w1[0][1]; b0.w[2] = w1[1][0]; b0.w[3] = w1[1][1];
#pragma unroll
  for (int dt = 0; dt < 4; dt++) {
    oacc0[dt] = mfma16(a0.v, vf[dt], oacc0[dt]);
    oacc1[dt] = mfma16(b0.v, vf[dt], oacc1[dt]);
  }
  lacc0 = mfma16(a0.v, onesf, lacc0);
  lacc1 = mfma16(b0.v, onesf, lacc1);
}

__global__ __launch_bounds__(256, 4) void k_attn(const unsigned short* __restrict__ Q,
                                                 const unsigned short* __restrict__ K,
                                                 const unsigned short* __restrict__ Vt,
                                                 unsigned short* __restrict__ O) {
  __shared__ unsigned short lsK[2][KVB * 64];      // 8KB each (merge O reuses)
  __shared__ unsigned short lsV[2][64 * KVB];      // 8KB each (merge l reuses)
  // bijective XCD swizzle: 128 consecutive vv (= 2 bh) per XCD -> K/V L2-resident
  int gid = blockIdx.x;                            // 1024 blocks
  int vv  = (gid & 7) * 128 + (gid >> 3);
  int bh  = vv >> 6;
  int tid = threadIdx.x, lane = tid & 63, wid = tid >> 6;
  int pair = wid >> 1, half = wid & 1;
  int g = lane >> 4, lr = lane & 15;
  int qw = (vv & 63) * 64 + pair * 32;
  const unsigned short* Qp = Q + (size_t)bh * NTOK * HD;
  const unsigned short* Kp = K + (size_t)bh * NTOK * HD;
  const unsigned short* Vp = Vt + (size_t)bh * HD * NTOK;
  unsigned short* K0 = &lsK[0][0]; unsigned short* K1 = &lsK[1][0];
  unsigned short* V0 = &lsV[0][0]; unsigned short* V1 = &lsV[1][0];

  union { unsigned short u[8]; bf16x8 v; } ou;
#pragma unroll
  for (int i = 0; i < 8; i++) ou.u[i] = 0x3F80;   // bf16 1.0
  bf16x8 onesf = ou.v;

  bf16x8 qf[2][2];
#pragma unroll
  for (int sq = 0; sq < 2; sq++)
#pragma unroll
    for (int ks = 0; ks < 2; ks++)
      qf[sq][ks] = *reinterpret_cast<const bf16x8*>(
          &Qp[(size_t)(qw + sq * 16 + lr) * HD + ks * 32 + 8 * g]);

  f32x4 zz = {0.f, 0.f, 0.f, 0.f};
  f32x4 oacc0[4] = {zz, zz, zz, zz};
  f32x4 oacc1[4] = {zz, zz, zz, zz};
  f32x4 lacc0 = zz, lacc1 = zz;

  stage_kv(Kp, Vp, K0, V0, 0, wid, lane);
  __syncthreads();

  for (int t = 0; t < NT; t += 2) {
    stage_kv(Kp, Vp, K1, V1, (t + 1) * KVB, wid, lane);
    attn_tile(K0, V0, half, qf, oacc0, oacc1, lacc0, lacc1, onesf, g, lr);
    __syncthreads();
    if (t + 2 < NT) stage_kv(Kp, Vp, K0, V0, (t + 2) * KVB, wid, lane);
    attn_tile(K1, V1, half, qf, oacc0, oacc1, lacc0, lacc1, onesf, g, lr);
    __syncthreads();
  }
  // ---- in-block merge of kv-half partials (additive: no-max softmax) ----
  float* mO = (float*)&lsK[0][0];    // [pair][32 q][64 d] f32 = 16KB
  float* mL = (float*)&lsV[0][0];    // [pair][32 q] f32
  if (half) {
#pragma unroll
    for (int sq = 0; sq < 2; sq++) {
      f32x4* oacc = sq ? oacc1 : oacc0;
      f32x4  lacc = sq ? lacc1 : lacc0;
#pragma unroll
      for (int r = 0; r < 4; r++) {
        int q = pair * 32 + sq * 16 + 4 * g + r;
#pragma unroll
        for (int dt = 0; dt < 4; dt++) mO[(q << 6) + dt * 16 + lr] = oacc[dt][r];
        if (lr == 0) mL[q] = lacc[r];
      }
    }
  }
  __syncthreads();
  if (!half) {
    int b2 = bh >> 3, h = bh & 7;
#pragma unroll
    for (int sq = 0; sq < 2; sq++) {
      f32x4* oacc = sq ? oacc1 : oacc0;
      f32x4  lacc = sq ? lacc1 : lacc0;
#pragma unroll
      for (int r = 0; r < 4; r++) {
        int q = pair * 32 + sq * 16 + 4 * g + r;
        float inv = 1.0f / (lacc[r] + mL[q]);
        int n = qw + sq * 16 + 4 * g + r;
#pragma unroll
        for (int dt = 0; dt < 4; dt++) {
          int d = dt * 16 + lr;
          float o = oacc[dt][r] + mO[(q << 6) + dt * 16 + lr];
          O[((size_t)(b2 * NTOK + n)) * CH + h * HD + d] = f2bf(o * inv);
        }
      }
    }
  }
}

// ---------------- kernel 5: out-proj GEMM + bias + residual -> res bf16 ----------------
// BM=64 (512 blocks, 2/CU), BN=128
__global__ __launch_bounds__(256) void k_gemm_out(const unsigned short* __restrict__ A,
                                                  const unsigned short* __restrict__ W,
                                                  const float* __restrict__ bias,
                                                  const unsigned short* __restrict__ tokB,
                                                  unsigned short* __restrict__ res) {
  __shared__ unsigned short lsA[64 * BK];
  __shared__ unsigned short lsB[128 * BK];
  int bm0 = blockIdx.x * 64;
  int bn0 = blockIdx.y * 128;
  int tid = threadIdx.x, lane = tid & 63, wid = tid >> 6;
  int wm = wid >> 1, wn = wid & 1;

  f32x4 acc[2][4];
  f32x4 zz = {0.f, 0.f, 0.f, 0.f};
#pragma unroll
  for (int i = 0; i < 2; i++)
#pragma unroll
    for (int j = 0; j < 4; j++) acc[i][j] = zz;

  for (int k0 = 0; k0 < 512; k0 += BK) {
    stage_g64(A, (size_t)bm0, k0, lsA, wid, lane);
    stage_g(W, (size_t)bn0, k0, lsB, wid, lane);
    __syncthreads();
#pragma unroll
    for (int ks = 0; ks < 2; ks++) {
      bf16x8 af[2], bfr[4];
#pragma unroll
      for (int t = 0; t < 2; t++)
        af[t] = frag_ld(lsA, wm * 32 + t * 16 + (lane & 15), ks, lane);
#pragma unroll
      for (int t = 0; t < 4; t++)
        bfr[t] = frag_ld(lsB, wn * 64 + t * 16 + (lane & 15), ks, lane);
#pragma unroll
      for (int mt = 0; mt < 2; mt++)
#pragma unroll
        for (int nt = 0; nt < 4; nt++) acc[mt][nt] = mfma16(af[mt], bfr[nt], acc[mt][nt]);
    }
    __syncthreads();
  }
#pragma unroll
  for (int nt = 0; nt < 4; nt++) {
    int j = bn0 + wn * 64 + nt * 16 + (lane & 15);
    float bj = bias[j];
#pragma unroll
    for (int mt = 0; mt < 2; mt++) {
#pragma unroll
      for (int r = 0; r < 4; r++) {
        int m = bm0 + wm * 32 + mt * 16 + 4 * (lane >> 4) + r;
        size_t idx = (size_t)m * CH + j;
        float tk = __uint_as_float((unsigned int)tokB[idx] << 16);
        res[idx] = f2bf(acc[mt][nt][r] + bj + tk);
      }
    }
  }
}

// ---------------- kernel 6: LayerNorm over C (bf16 res) + transposed write ----------------
__global__ __launch_bounds__(256) void k_ln(const unsigned short* __restrict__ res,
                                            const float* __restrict__ g,
                                            const float* __restrict__ bb,
                                            float* __restrict__ y) {
  __shared__ float smean[64], srstd[64];
  int m0 = blockIdx.x * 64;
  int tid = threadIdx.x, lane = tid & 63, wid = tid >> 6;
  for (int t = 0; t < 16; t++) {
    int idx = wid * 16 + t;
    uint4 v = *reinterpret_cast<const uint4*>(&res[(size_t)(m0 + idx) * CH + lane * 8]);
    unsigned int wv[4] = {v.x, v.y, v.z, v.w};
    float s = 0.f, ss = 0.f;
#pragma unroll
    for (int j = 0; j < 4; j++) {
      float lo = __uint_as_float(wv[j] << 16);
      float hi = __uint_as_float(wv[j] & 0xFFFF0000u);
      s += lo + hi; ss += lo * lo + hi * hi;
    }
#pragma unroll
    for (int off = 1; off < 64; off <<= 1) {
      s += __shfl_xor(s, off);
      ss += __shfl_xor(ss, off);
    }
    if (lane == 0) {
      float mean = s * (1.0f / CH);
      float var = ss * (1.0f / CH) - mean * mean;
      smean[idx] = mean;
      srstd[idx] = rsqrtf(var + 1e-5f);
    }
  }
  __syncthreads();
  int b = m0 >> 12, n0 = m0 & 4095;
  int tn = tid & 63;
  int cq = tid >> 6;
  float mn = smean[tn], rs = srstd[tn];
  const unsigned short* rrow = res + (size_t)(m0 + tn) * CH;
  float* yb = y + ((size_t)b * CH) * NTOK + n0 + tn;
#pragma unroll
  for (int i = 0; i < 16; i++) {
    int c = cq * 128 + i * 8;
    uint4 v = *reinterpret_cast<const uint4*>(&rrow[c]);
    unsigned int wv[4] = {v.x, v.y, v.z, v.w};
    float4 ga = *reinterpret_cast<const float4*>(&g[c]);
    float4 gb = *reinterpret_cast<const float4*>(&g[c + 4]);
    float4 ba = *reinterpret_cast<const float4*>(&bb[c]);
    float4 b4 = *reinterpret_cast<const float4*>(&bb[c + 4]);
    float gg[8] = {ga.x, ga.y, ga.z, ga.w, gb.x, gb.y, gb.z, gb.w};
    float bv[8] = {ba.x, ba.y, ba.z, ba.w, b4.x, b4.y, b4.z, b4.w};
#pragma unroll
    for (int j = 0; j < 4; j++) {
      float lo = __uint_as_float(wv[j] << 16);
      float hi = __uint_as_float(wv[j] & 0xFFFF0000u);
      yb[(size_t)(c + 2 * j) * NTOK]     = (lo - mn) * rs * gg[2 * j]     + bv[2 * j];
      yb[(size_t)(c + 2 * j + 1) * NTOK] = (hi - mn) * rs * gg[2 * j + 1] + bv[2 * j + 1];
    }
  }
}

// ---------------- launch ----------------
extern "C" void kernel_launch(void* const* d_in, const int* in_sizes, int n_in,
                              void* d_out, int out_size, void* d_ws, size_t ws_size,
                              hipStream_t stream) {
  const float* x    = (const float*)d_in[0];
  const float* qkvw = (const float*)d_in[1];
  const float* qkvb = (const float*)d_in[2];
  const float* outw = (const float*)d_in[3];
  const float* outb = (const float*)d_in[4];
  const float* lng  = (const float*)d_in[5];
  const float* lnb  = (const float*)d_in[6];
  float* y = (float*)d_out;

  const size_t NC = (size_t)MTOT * CH;   // 4.2M elements
  char* ws = (char*)d_ws;
  size_t off = 0;
  auto nxt = [&](size_t bytes) -> void* {
    void* p = ws + off;
    off += (bytes + 255) & ~(size_t)255;
    return p;
  };
  unsigned short* tokB = (unsigned short*)nxt(NC * 2);
  unsigned short* wqkv = (unsigned short*)nxt((size_t)3 * CH * CH * 2);
  unsigned short* wout = (unsigned short*)nxt((size_t)CH * CH * 2);
  unsigned short* qb   = (unsigned short*)nxt(NC * 2);
  unsigned short* kb   = (unsigned short*)nxt(NC * 2);
  unsigned short* vt   = (unsigned short*)nxt(NC * 2);
  unsigned short* ao   = (unsigned short*)nxt(NC * 2);
  unsigned short* resb = (unsigned short*)nxt(NC * 2);
  if (off > ws_size) return;

  k_transpose<<<dim3(NTOK / 32, CH / 32, BATCH), 256, 0, stream>>>(x, tokB);
  k_castw<<<(4 * CH * CH) / 256, 256, 0, stream>>>(qkvw, outw, wqkv, wout);
  k_gemm_qkv<<<dim3(MTOT / 128, (3 * CH) / 128), 256, 0, stream>>>(tokB, wqkv, qkvb, qb, kb, vt);
  k_attn<<<1024, 256, 0, stream>>>(qb, kb, vt, ao);
  k_gemm_out<<<dim3(MTOT / 64, CH / 128), 256, 0, stream>>>(ao, wout, outb, tokB, resb);
  k_ln<<<MTOT / 64, 256, 0, stream>>>(resb, lng, lnb, y);
}

// Round 13
// 165.802 us; speedup vs baseline: 1.0224x; 1.0084x over previous
//
#include <hip/hip_runtime.h>

// ---------------- problem constants ----------------
#define BATCH 2
#define CH    512
#define NTOK  4096      // H*W
#define NH    8
#define HD    64
#define MTOT  (BATCH*NTOK)   // 8192

typedef __attribute__((ext_vector_type(8))) __bf16 bf16x8;
typedef __attribute__((ext_vector_type(4))) float  f32x4;
typedef __attribute__((ext_vector_type(4))) unsigned short u16x4;

static __device__ __forceinline__ f32x4 mfma16(bf16x8 a, bf16x8 b, f32x4 c) {
  return __builtin_amdgcn_mfma_f32_16x16x32_bf16(a, b, c, 0, 0, 0);
}

static __device__ __forceinline__ unsigned short f2bf(float f) {
  unsigned int u = __float_as_uint(f);
  u += 0x7fffu + ((u >> 16) & 1u);
  return (unsigned short)(u >> 16);
}

static __device__ __forceinline__ void gload_lds16(const unsigned short* g, unsigned short* l) {
  __builtin_amdgcn_global_load_lds((const __attribute__((address_space(1))) void*)g,
                                   (__attribute__((address_space(3))) void*)l, 16, 0, 0);
}

// q pre-scale: (1/sqrt(HD)) * log2(e)  -> QK^T lands directly in exp2 domain
#define QSC 0.18033688011112042f

// ---------------- kernel 1: x [B,C,N] -> tokens [B,N,C] bf16 ----------------
__global__ __launch_bounds__(256) void k_transpose(const float* __restrict__ x,
                                                   unsigned short* __restrict__ tokB) {
  __shared__ float tile[32][33];
  int b  = blockIdx.z;
  int n0 = blockIdx.x * 32;
  int c0 = blockIdx.y * 32;
  int tx = threadIdx.x & 31, ty = threadIdx.x >> 5;  // 32 x 8
#pragma unroll
  for (int i = 0; i < 4; i++) {
    int c = c0 + ty + 8 * i;
    tile[ty + 8 * i][tx] = x[((size_t)b * CH + c) * NTOK + n0 + tx];
  }
  __syncthreads();
#pragma unroll
  for (int i = 0; i < 4; i++) {
    int n = n0 + ty + 8 * i;
    int c = c0 + tx;
    tokB[((size_t)b * NTOK + n) * CH + c] = f2bf(tile[tx][ty + 8 * i]);
  }
}

// ---------------- kernel 2: both weight casts in one launch ----------------
__global__ __launch_bounds__(256) void k_castw(const float* __restrict__ w1,
                                               const float* __restrict__ w2,
                                               unsigned short* __restrict__ o1,
                                               unsigned short* __restrict__ o2) {
  int i = blockIdx.x * 256 + threadIdx.x;
  if (i < 3 * CH * CH) o1[i] = f2bf(w1[i]);
  else o2[i - 3 * CH * CH] = f2bf(w2[i - 3 * CH * CH]);
}

// ---------------- GEMM helpers ----------------
#define BK 64

// async-stage one 128x64 bf16 tile into swizzled LDS via global_load_lds.
static __device__ __forceinline__ void stage_g(const unsigned short* __restrict__ src,
                                               size_t row0, int k0,
                                               unsigned short* __restrict__ lds,
                                               int wid, int lane) {
  int sub = lane >> 3;               // 0..7 : row within 8-row group
  int ch  = (lane & 7) ^ sub;        // pre-swizzled source chunk
#pragma unroll
  for (int i = 0; i < 4; i++) {
    int rbase = 32 * wid + 8 * i;
    gload_lds16(&src[(row0 + rbase + sub) * 512 + k0 + ch * 8], &lds[rbase * BK]);
  }
}

// 64-row variant
static __device__ __forceinline__ void stage_g64(const unsigned short* __restrict__ src,
                                                 size_t row0, int k0,
                                                 unsigned short* __restrict__ lds,
                                                 int wid, int lane) {
  int sub = lane >> 3;
  int ch  = (lane & 7) ^ sub;
#pragma unroll
  for (int i = 0; i < 2; i++) {
    int rbase = 16 * wid + 8 * i;
    gload_lds16(&src[(row0 + rbase + sub) * 512 + k0 + ch * 8], &lds[rbase * BK]);
  }
}

static __device__ __forceinline__ bf16x8 frag_ld(const unsigned short* __restrict__ lds,
                                                 int row, int ks, int lane) {
  int ch = ((ks << 2) + (lane >> 4)) ^ (row & 7);
  return *reinterpret_cast<const bf16x8*>(&lds[row * BK + ch * 8]);
}

// ---------------- kernel 3: QKV GEMM -> q(pre-scaled)/k [B,H,N,D], V^T [B,H,D,N] ----------------
__global__ __launch_bounds__(256) void k_gemm_qkv(const unsigned short* __restrict__ A,
                                                  const unsigned short* __restrict__ W,
                                                  const float* __restrict__ bias,
                                                  unsigned short* __restrict__ qb,
                                                  unsigned short* __restrict__ kb,
                                                  unsigned short* __restrict__ vt) {
  __shared__ unsigned short lsA[128 * BK];
  __shared__ unsigned short lsB[128 * BK];
  int bm0 = blockIdx.x * 128;
  int bn0 = blockIdx.y * 128;
  int tid = threadIdx.x, lane = tid & 63, wid = tid >> 6;
  int wm = wid >> 1, wn = wid & 1;

  f32x4 acc[4][4];
  f32x4 zz = {0.f, 0.f, 0.f, 0.f};
#pragma unroll
  for (int i = 0; i < 4; i++)
#pragma unroll
    for (int j = 0; j < 4; j++) acc[i][j] = zz;

  for (int k0 = 0; k0 < 512; k0 += BK) {
    stage_g(A, (size_t)bm0, k0, lsA, wid, lane);
    stage_g(W, (size_t)bn0, k0, lsB, wid, lane);
    __syncthreads();
#pragma unroll
    for (int ks = 0; ks < 2; ks++) {
      bf16x8 af[4], bfr[4];
#pragma unroll
      for (int t = 0; t < 4; t++) {
        af[t]  = frag_ld(lsA, wm * 64 + t * 16 + (lane & 15), ks, lane);
        bfr[t] = frag_ld(lsB, wn * 64 + t * 16 + (lane & 15), ks, lane);
      }
#pragma unroll
      for (int mt = 0; mt < 4; mt++)
#pragma unroll
        for (int nt = 0; nt < 4; nt++) acc[mt][nt] = mfma16(af[mt], bfr[nt], acc[mt][nt]);
    }
    __syncthreads();
  }
#pragma unroll
  for (int nt = 0; nt < 4; nt++) {
    int j = bn0 + wn * 64 + nt * 16 + (lane & 15);
    float bj = bias[j];
    int which = j >> 9;        // wave-uniform
    int cp = j & 511;
    int h = cp >> 6, d = cp & 63;
    if (which == 2) {
#pragma unroll
      for (int mt = 0; mt < 4; mt++) {
        int m = bm0 + wm * 64 + mt * 16 + 4 * (lane >> 4);
        int b = m >> 12, n = m & 4095;
        u16x4 pk;
#pragma unroll
        for (int r = 0; r < 4; r++) pk[r] = f2bf(acc[mt][nt][r] + bj);
        *reinterpret_cast<u16x4*>(&vt[((size_t)((b * NH + h) * HD + d)) * NTOK + n]) = pk;
      }
    } else {
      unsigned short* dst = (which == 0) ? qb : kb;
      float sc = (which == 0) ? QSC : 1.0f;
#pragma unroll
      for (int mt = 0; mt < 4; mt++) {
#pragma unroll
        for (int r = 0; r < 4; r++) {
          int m = bm0 + wm * 64 + mt * 16 + 4 * (lane >> 4) + r;
          int b = m >> 12, n = m & 4095;
          dst[(((size_t)(b * NH + h) * NTOK + n) << 6) + d] = f2bf((acc[mt][nt][r] + bj) * sc);
        }
      }
    }
  }
}

// ---------------- kernel 4: flash attention ----------------
// Block = 4 waves, 64 q/block, 1024 blocks (3/CU). Wave w: q-pair (w>>1, 32 q)
// x kv-half (w&1). 3-slot LDS rotation with COUNTED vmcnt(4) across a raw
// s_barrier (T3/T4 minimum: staging loads stay in flight across barriers, never
// drained to 0 in-loop). sigma in-register P; no-max softmax; l via ones-MFMA;
// kv-half partials additive -> in-block LDS merge; bijective XCD swizzle.
#define KVB 64
#define NT  (NTOK / KVB)   // 64

static __device__ __forceinline__ void stage_kv(const unsigned short* __restrict__ Kp,
                                                const unsigned short* __restrict__ Vp,
                                                unsigned short* __restrict__ lk,
                                                unsigned short* __restrict__ lv,
                                                int kv0, int wid, int lane) {
  int sub = lane >> 3;        // row within 8-row group
  int c7  = lane & 7;         // dest chunk
#pragma unroll
  for (int i = 0; i < 2; i++) {
    int rbase = 16 * wid + 8 * i;
    int row = rbase + sub;
    int fk = (sub & 3) | (i << 2);          // f(row) for K (sigma key)
    gload_lds16(&Kp[((size_t)(kv0 + row) << 6) + ((c7 ^ fk) << 3)], &lk[rbase << 6]);
    gload_lds16(&Vp[(size_t)row * NTOK + kv0 + ((c7 ^ sub) << 3)], &lv[rbase << 6]);
  }
}

static __device__ __forceinline__ void attn_tile(const unsigned short* __restrict__ lk,
                                                 const unsigned short* __restrict__ lv,
                                                 int half,
                                                 const bf16x8 qf[2][2],
                                                 f32x4* oacc0, f32x4* oacc1,
                                                 f32x4& lacc0, f32x4& lacc1,
                                                 bf16x8 onesf, int g, int lr) {
  f32x4 zz = {0.f, 0.f, 0.f, 0.f};
  int l7 = lr & 7;
  int tbase = 32 * half + 8 * (lr >> 2) + (lr & 3);
  int kc0 = (g ^ l7) << 3;
  int kc1 = ((4 + g) ^ l7) << 3;
  // K fragments (sigma row order), kv-half of the tile
  bf16x8 kf[2][2];
#pragma unroll
  for (int ct = 0; ct < 2; ct++) {
    int t = tbase + 4 * ct;
    kf[ct][0] = *reinterpret_cast<const bf16x8*>(&lk[(t << 6) + kc0]);
    kf[ct][1] = *reinterpret_cast<const bf16x8*>(&lk[(t << 6) + kc1]);
  }
  f32x4 s0[2], s1[2];
#pragma unroll
  for (int ct = 0; ct < 2; ct++) {
    s0[ct] = mfma16(kf[ct][0], qf[0][0], zz);
    s0[ct] = mfma16(kf[ct][1], qf[0][1], s0[ct]);
    s1[ct] = mfma16(kf[ct][0], qf[1][0], zz);
    s1[ct] = mfma16(kf[ct][1], qf[1][1], s1[ct]);
  }
  // V fragments for this kv-half (issue early; hides under softmax)
  bf16x8 vf[4];
  int vc = (((half << 2) + g) ^ l7) << 3;
#pragma unroll
  for (int dt = 0; dt < 4; dt++)
    vf[dt] = *reinterpret_cast<const bf16x8*>(&lv[((dt * 16 + lr) << 6) + vc]);
  // softmax: exp2 then pack straight into PV A-fragments (in-register)
#pragma unroll
  for (int ct = 0; ct < 2; ct++) {
#pragma unroll
    for (int r = 0; r < 4; r++) {
      s0[ct][r] = __builtin_exp2f(s0[ct][r]);
      s1[ct][r] = __builtin_exp2f(s1[ct][r]);
    }
  }
  unsigned int w0[2][2], w1[2][2];
#pragma unroll
  for (int ct = 0; ct < 2; ct++) {
    asm("v_cvt_pk_bf16_f32 %0, %1, %2" : "=v"(w0[ct][0]) : "v"(s0[ct][0]), "v"(s0[ct][1]));
    asm("v_cvt_pk_bf16_f32 %0, %1, %2" : "=v"(w0[ct][1]) : "v"(s0[ct][2]), "v"(s0[ct][3]));
    asm("v_cvt_pk_bf16_f32 %0, %1, %2" : "=v"(w1[ct][0]) : "v"(s1[ct][0]), "v"(s1[ct][1]));
    asm("v_cvt_pk_bf16_f32 %0, %1, %2" : "=v"(w1[ct][1]) : "v"(s1[ct][2]), "v"(s1[ct][3]));
  }
  union U { unsigned int w[4]; bf16x8 v; };
  U a0, b0;
  a0.w[0] = w0[0][0]; a0.w[1] = w0[0][1]; a0.w[2] = w0[1][0]; a0.w[3] = w0[1][1]; // k=8g..8g+7
  b0.w[0] = w1[0][0]; b0.w[1] = w1[0][1]; b0.w[2] = w1[1][0]; b0.w[3] = w1[1][1];
#pragma unroll
  for (int dt = 0; dt < 4; dt++) {
    oacc0[dt] = mfma16(a0.v, vf[dt], oacc0[dt]);
    oacc1[dt] = mfma16(b0.v, vf[dt], oacc1[dt]);
  }
  lacc0 = mfma16(a0.v, onesf, lacc0);
  lacc1 = mfma16(b0.v, onesf, lacc1);
}

__global__ __launch_bounds__(256, 3) void k_attn(const unsigned short* __restrict__ Q,
                                                 const unsigned short* __restrict__ K,
                                                 const unsigned short* __restrict__ Vt,
                                                 unsigned short* __restrict__ O) {
  __shared__ unsigned short lsK[3][KVB * 64];      // 8KB each (merge O reuses [0..1])
  __shared__ unsigned short lsV[3][64 * KVB];      // 8KB each (merge l reuses [0])
  // bijective XCD swizzle: 128 consecutive vv (= 2 bh) per XCD -> K/V L2-resident
  int gid = blockIdx.x;                            // 1024 blocks
  int vv  = (gid & 7) * 128 + (gid >> 3);
  int bh  = vv >> 6;
  int tid = threadIdx.x, lane = tid & 63, wid = tid >> 6;
  int pair = wid >> 1, half = wid & 1;
  int g = lane >> 4, lr = lane & 15;
  int qw = (vv & 63) * 64 + pair * 32;
  const unsigned short* Qp = Q + (size_t)bh * NTOK * HD;
  const unsigned short* Kp = K + (size_t)bh * NTOK * HD;
  const unsigned short* Vp = Vt + (size_t)bh * HD * NTOK;

  union { unsigned short u[8]; bf16x8 v; } ou;
#pragma unroll
  for (int i = 0; i < 8; i++) ou.u[i] = 0x3F80;   // bf16 1.0
  bf16x8 onesf = ou.v;

  bf16x8 qf[2][2];
#pragma unroll
  for (int sq = 0; sq < 2; sq++)
#pragma unroll
    for (int ks = 0; ks < 2; ks++)
      qf[sq][ks] = *reinterpret_cast<const bf16x8*>(
          &Qp[(size_t)(qw + sq * 16 + lr) * HD + ks * 32 + 8 * g]);

  f32x4 zz = {0.f, 0.f, 0.f, 0.f};
  f32x4 oacc0[4] = {zz, zz, zz, zz};
  f32x4 oacc1[4] = {zz, zz, zz, zz};
  f32x4 lacc0 = zz, lacc1 = zz;

  // 3-slot rotation (pointers, not runtime indexing)
  unsigned short *kA = &lsK[0][0], *kB = &lsK[1][0], *kC = &lsK[2][0];
  unsigned short *vA = &lsV[0][0], *vB = &lsV[1][0], *vC = &lsV[2][0];

  // prologue: stage tiles 0,1 into slots A,B (8 loads in flight)
  stage_kv(Kp, Vp, kA, vA, 0, wid, lane);
  stage_kv(Kp, Vp, kB, vB, KVB, wid, lane);

  for (int t = 0; t < NT; t++) {
    // counted wait: tile t's 4 loads (issued 2 iterations ago) done;
    // tile t+1's 4 stay in flight across the barrier.
    if (t < NT - 1) asm volatile("s_waitcnt vmcnt(4)" ::: "memory");
    else            asm volatile("s_waitcnt vmcnt(0)" ::: "memory");
    __builtin_amdgcn_s_barrier();
    asm volatile("" ::: "memory");
    // stage tile t+2 into the slot freed by compute(t-1) (WAR-safe: all waves
    // passed the barrier, hence finished compute(t-1))
    if (t + 2 < NT) stage_kv(Kp, Vp, kC, vC, (t + 2) * KVB, wid, lane);
    attn_tile(kA, vA, half, qf, oacc0, oacc1, lacc0, lacc1, onesf, g, lr);
    // rotate slots
    unsigned short* tk = kA; kA = kB; kB = kC; kC = tk;
    unsigned short* tv = vA; vA = vB; vB = vC; vC = tv;
  }
  __syncthreads();   // all compute done before LDS reuse for merge
  // ---- in-block merge of kv-half partials (additive: no-max softmax) ----
  float* mO = (float*)&lsK[0][0];    // [pair][32 q][64 d] f32 = 16KB (slots 0-1)
  float* mL = (float*)&lsV[0][0];    // [pair][32 q] f32
  if (half) {
#pragma unroll
    for (int sq = 0; sq < 2; sq++) {
      f32x4* oacc = sq ? oacc1 : oacc0;
      f32x4  lacc = sq ? lacc1 : lacc0;
#pragma unroll
      for (int r = 0; r < 4; r++) {
        int q = pair * 32 + sq * 16 + 4 * g + r;
#pragma unroll
        for (int dt = 0; dt < 4; dt++) mO[(q << 6) + dt * 16 + lr] = oacc[dt][r];
        if (lr == 0) mL[q] = lacc[r];
      }
    }
  }
  __syncthreads();
  if (!half) {
    int b2 = bh >> 3, h = bh & 7;
#pragma unroll
    for (int sq = 0; sq < 2; sq++) {
      f32x4* oacc = sq ? oacc1 : oacc0;
      f32x4  lacc = sq ? lacc1 : lacc0;
#pragma unroll
      for (int r = 0; r < 4; r++) {
        int q = pair * 32 + sq * 16 + 4 * g + r;
        float inv = 1.0f / (lacc[r] + mL[q]);
        int n = qw + sq * 16 + 4 * g + r;
#pragma unroll
        for (int dt = 0; dt < 4; dt++) {
          int d = dt * 16 + lr;
          float o = oacc[dt][r] + mO[(q << 6) + dt * 16 + lr];
          O[((size_t)(b2 * NTOK + n)) * CH + h * HD + d] = f2bf(o * inv);
        }
      }
    }
  }
}

// ---------------- kernel 5: out-proj GEMM + bias + residual -> res bf16 ----------------
// BM=64 (512 blocks, 2/CU), BN=128
__global__ __launch_bounds__(256) void k_gemm_out(const unsigned short* __restrict__ A,
                                                  const unsigned short* __restrict__ W,
                                                  const float* __restrict__ bias,
                                                  const unsigned short* __restrict__ tokB,
                                                  unsigned short* __restrict__ res) {
  __shared__ unsigned short lsA[64 * BK];
  __shared__ unsigned short lsB[128 * BK];
  int bm0 = blockIdx.x * 64;
  int bn0 = blockIdx.y * 128;
  int tid = threadIdx.x, lane = tid & 63, wid = tid >> 6;
  int wm = wid >> 1, wn = wid & 1;

  f32x4 acc[2][4];
  f32x4 zz = {0.f, 0.f, 0.f, 0.f};
#pragma unroll
  for (int i = 0; i < 2; i++)
#pragma unroll
    for (int j = 0; j < 4; j++) acc[i][j] = zz;

  for (int k0 = 0; k0 < 512; k0 += BK) {
    stage_g64(A, (size_t)bm0, k0, lsA, wid, lane);
    stage_g(W, (size_t)bn0, k0, lsB, wid, lane);
    __syncthreads();
#pragma unroll
    for (int ks = 0; ks < 2; ks++) {
      bf16x8 af[2], bfr[4];
#pragma unroll
      for (int t = 0; t < 2; t++)
        af[t] = frag_ld(lsA, wm * 32 + t * 16 + (lane & 15), ks, lane);
#pragma unroll
      for (int t = 0; t < 4; t++)
        bfr[t] = frag_ld(lsB, wn * 64 + t * 16 + (lane & 15), ks, lane);
#pragma unroll
      for (int mt = 0; mt < 2; mt++)
#pragma unroll
        for (int nt = 0; nt < 4; nt++) acc[mt][nt] = mfma16(af[mt], bfr[nt], acc[mt][nt]);
    }
    __syncthreads();
  }
#pragma unroll
  for (int nt = 0; nt < 4; nt++) {
    int j = bn0 + wn * 64 + nt * 16 + (lane & 15);
    float bj = bias[j];
#pragma unroll
    for (int mt = 0; mt < 2; mt++) {
#pragma unroll
      for (int r = 0; r < 4; r++) {
        int m = bm0 + wm * 32 + mt * 16 + 4 * (lane >> 4) + r;
        size_t idx = (size_t)m * CH + j;
        float tk = __uint_as_float((unsigned int)tokB[idx] << 16);
        res[idx] = f2bf(acc[mt][nt][r] + bj + tk);
      }
    }
  }
}

// ---------------- kernel 6: LayerNorm over C (bf16 res) + transposed write ----------------
__global__ __launch_bounds__(256) void k_ln(const unsigned short* __restrict__ res,
                                            const float* __restrict__ g,
                                            const float* __restrict__ bb,
                                            float* __restrict__ y) {
  __shared__ float smean[64], srstd[64];
  int m0 = blockIdx.x * 64;
  int tid = threadIdx.x, lane = tid & 63, wid = tid >> 6;
  for (int t = 0; t < 16; t++) {
    int idx = wid * 16 + t;
    uint4 v = *reinterpret_cast<const uint4*>(&res[(size_t)(m0 + idx) * CH + lane * 8]);
    unsigned int wv[4] = {v.x, v.y, v.z, v.w};
    float s = 0.f, ss = 0.f;
#pragma unroll
    for (int j = 0; j < 4; j++) {
      float lo = __uint_as_float(wv[j] << 16);
      float hi = __uint_as_float(wv[j] & 0xFFFF0000u);
      s += lo + hi; ss += lo * lo + hi * hi;
    }
#pragma unroll
    for (int off = 1; off < 64; off <<= 1) {
      s += __shfl_xor(s, off);
      ss += __shfl_xor(ss, off);
    }
    if (lane == 0) {
      float mean = s * (1.0f / CH);
      float var = ss * (1.0f / CH) - mean * mean;
      smean[idx] = mean;
      srstd[idx] = rsqrtf(var + 1e-5f);
    }
  }
  __syncthreads();
  int b = m0 >> 12, n0 = m0 & 4095;
  int tn = tid & 63;
  int cq = tid >> 6;
  float mn = smean[tn], rs = srstd[tn];
  const unsigned short* rrow = res + (size_t)(m0 + tn) * CH;
  float* yb = y + ((size_t)b * CH) * NTOK + n0 + tn;
#pragma unroll
  for (int i = 0; i < 16; i++) {
    int c = cq * 128 + i * 8;
    uint4 v = *reinterpret_cast<const uint4*>(&rrow[c]);
    unsigned int wv[4] = {v.x, v.y, v.z, v.w};
    float4 ga = *reinterpret_cast<const float4*>(&g[c]);
    float4 gb = *reinterpret_cast<const float4*>(&g[c + 4]);
    float4 ba = *reinterpret_cast<const float4*>(&bb[c]);
    float4 b4 = *reinterpret_cast<const float4*>(&bb[c + 4]);
    float gg[8] = {ga.x, ga.y, ga.z, ga.w, gb.x, gb.y, gb.z, gb.w};
    float bv[8] = {ba.x, ba.y, ba.z, ba.w, b4.x, b4.y, b4.z, b4.w};
#pragma unroll
    for (int j = 0; j < 4; j++) {
      float lo = __uint_as_float(wv[j] << 16);
      float hi = __uint_as_float(wv[j] & 0xFFFF0000u);
      yb[(size_t)(c + 2 * j) * NTOK]     = (lo - mn) * rs * gg[2 * j]     + bv[2 * j];
      yb[(size_t)(c + 2 * j + 1) * NTOK] = (hi - mn) * rs * gg[2 * j + 1] + bv[2 * j + 1];
    }
  }
}

// ---------------- launch ----------------
extern "C" void kernel_launch(void* const* d_in, const int* in_sizes, int n_in,
                              void* d_out, int out_size, void* d_ws, size_t ws_size,
                              hipStream_t stream) {
  const float* x    = (const float*)d_in[0];
  const float* qkvw = (const float*)d_in[1];
  const float* qkvb = (const float*)d_in[2];
  const float* outw = (const float*)d_in[3];
  const float* outb = (const float*)d_in[4];
  const float* lng  = (const float*)d_in[5];
  const float* lnb  = (const float*)d_in[6];
  float* y = (float*)d_out;

  const size_t NC = (size_t)MTOT * CH;   // 4.2M elements
  char* ws = (char*)d_ws;
  size_t off = 0;
  auto nxt = [&](size_t bytes) -> void* {
    void* p = ws + off;
    off += (bytes + 255) & ~(size_t)255;
    return p;
  };
  unsigned short* tokB = (unsigned short*)nxt(NC * 2);
  unsigned short* wqkv = (unsigned short*)nxt((size_t)3 * CH * CH * 2);
  unsigned short* wout = (unsigned short*)nxt((size_t)CH * CH * 2);
  unsigned short* qb   = (unsigned short*)nxt(NC * 2);
  unsigned short* kb   = (unsigned short*)nxt(NC * 2);
  unsigned short* vt   = (unsigned short*)nxt(NC * 2);
  unsigned short* ao   = (unsigned short*)nxt(NC * 2);
  unsigned short* resb = (unsigned short*)nxt(NC * 2);
  if (off > ws_size) return;

  k_transpose<<<dim3(NTOK / 32, CH / 32, BATCH), 256, 0, stream>>>(x, tokB);
  k_castw<<<(4 * CH * CH) / 256, 256, 0, stream>>>(qkvw, outw, wqkv, wout);
  k_gemm_qkv<<<dim3(MTOT / 128, (3 * CH) / 128), 256, 0, stream>>>(tokB, wqkv, qkvb, qb, kb, vt);
  k_attn<<<1024, 256, 0, stream>>>(qb, kb, vt, ao);
  k_gemm_out<<<dim3(MTOT / 64, CH / 128), 256, 0, stream>>>(ao, wout, outb, tokB, resb);
  k_ln<<<MTOT / 64, 256, 0, stream>>>(resb, lng, lnb, y);
}

// Round 14
// 157.422 us; speedup vs baseline: 1.0769x; 1.0532x over previous
//
#include <hip/hip_runtime.h>

// ---------------- problem constants ----------------
#define BATCH 2
#define CH    512
#define NTOK  4096      // H*W
#define NH    8
#define HD    64
#define MTOT  (BATCH*NTOK)   // 8192

typedef __attribute__((ext_vector_type(8))) __bf16 bf16x8;
typedef __attribute__((ext_vector_type(4))) float  f32x4;
typedef __attribute__((ext_vector_type(4))) unsigned short u16x4;

static __device__ __forceinline__ f32x4 mfma16(bf16x8 a, bf16x8 b, f32x4 c) {
  return __builtin_amdgcn_mfma_f32_16x16x32_bf16(a, b, c, 0, 0, 0);
}

static __device__ __forceinline__ unsigned short f2bf(float f) {
  unsigned int u = __float_as_uint(f);
  u += 0x7fffu + ((u >> 16) & 1u);
  return (unsigned short)(u >> 16);
}

static __device__ __forceinline__ void gload_lds16(const unsigned short* g, unsigned short* l) {
  __builtin_amdgcn_global_load_lds((const __attribute__((address_space(1))) void*)g,
                                   (__attribute__((address_space(3))) void*)l, 16, 0, 0);
}

// q pre-scale: (1/sqrt(HD)) * log2(e)  -> QK^T lands directly in exp2 domain
#define QSC 0.18033688011112042f

// ---------------- kernel 1: fused transpose (x -> tokens bf16) + weight casts ----------------
// blocks [0,4096): transpose 32x32 tiles; blocks [4096,8192): cast qkv_w/out_w
__global__ __launch_bounds__(256) void k_pre(const float* __restrict__ x,
                                             const float* __restrict__ w1,
                                             const float* __restrict__ w2,
                                             unsigned short* __restrict__ tokB,
                                             unsigned short* __restrict__ o1,
                                             unsigned short* __restrict__ o2) {
  __shared__ float tile[32][33];
  int bid = blockIdx.x;
  if (bid >= 4096) {
    int i = (bid - 4096) * 256 + threadIdx.x;
    if (i < 3 * CH * CH) o1[i] = f2bf(w1[i]);
    else o2[i - 3 * CH * CH] = f2bf(w2[i - 3 * CH * CH]);
    return;
  }
  int b  = bid >> 11;
  int n0 = (bid & 127) * 32;
  int c0 = ((bid >> 7) & 15) * 32;
  int tx = threadIdx.x & 31, ty = threadIdx.x >> 5;  // 32 x 8
#pragma unroll
  for (int i = 0; i < 4; i++) {
    int c = c0 + ty + 8 * i;
    tile[ty + 8 * i][tx] = x[((size_t)b * CH + c) * NTOK + n0 + tx];
  }
  __syncthreads();
#pragma unroll
  for (int i = 0; i < 4; i++) {
    int n = n0 + ty + 8 * i;
    int c = c0 + tx;
    tokB[((size_t)b * NTOK + n) * CH + c] = f2bf(tile[tx][ty + 8 * i]);
  }
}

// ---------------- GEMM helpers ----------------
#define BK 64

// async-stage one 128x64 bf16 tile into swizzled LDS via global_load_lds.
static __device__ __forceinline__ void stage_g(const unsigned short* __restrict__ src,
                                               size_t row0, int k0,
                                               unsigned short* __restrict__ lds,
                                               int wid, int lane) {
  int sub = lane >> 3;               // 0..7 : row within 8-row group
  int ch  = (lane & 7) ^ sub;        // pre-swizzled source chunk
#pragma unroll
  for (int i = 0; i < 4; i++) {
    int rbase = 32 * wid + 8 * i;
    gload_lds16(&src[(row0 + rbase + sub) * 512 + k0 + ch * 8], &lds[rbase * BK]);
  }
}

// 64-row variant
static __device__ __forceinline__ void stage_g64(const unsigned short* __restrict__ src,
                                                 size_t row0, int k0,
                                                 unsigned short* __restrict__ lds,
                                                 int wid, int lane) {
  int sub = lane >> 3;
  int ch  = (lane & 7) ^ sub;
#pragma unroll
  for (int i = 0; i < 2; i++) {
    int rbase = 16 * wid + 8 * i;
    gload_lds16(&src[(row0 + rbase + sub) * 512 + k0 + ch * 8], &lds[rbase * BK]);
  }
}

static __device__ __forceinline__ bf16x8 frag_ld(const unsigned short* __restrict__ lds,
                                                 int row, int ks, int lane) {
  int ch = ((ks << 2) + (lane >> 4)) ^ (row & 7);
  return *reinterpret_cast<const bf16x8*>(&lds[row * BK + ch * 8]);
}

// ---------------- kernel 3: QKV GEMM -> q(pre-scaled)/k [B,H,N,D], V^T [B,H,D,N] ----------------
__global__ __launch_bounds__(256) void k_gemm_qkv(const unsigned short* __restrict__ A,
                                                  const unsigned short* __restrict__ W,
                                                  const float* __restrict__ bias,
                                                  unsigned short* __restrict__ qb,
                                                  unsigned short* __restrict__ kb,
                                                  unsigned short* __restrict__ vt) {
  __shared__ unsigned short lsA[128 * BK];
  __shared__ unsigned short lsB[128 * BK];
  int bm0 = blockIdx.x * 128;
  int bn0 = blockIdx.y * 128;
  int tid = threadIdx.x, lane = tid & 63, wid = tid >> 6;
  int wm = wid >> 1, wn = wid & 1;

  f32x4 acc[4][4];
  f32x4 zz = {0.f, 0.f, 0.f, 0.f};
#pragma unroll
  for (int i = 0; i < 4; i++)
#pragma unroll
    for (int j = 0; j < 4; j++) acc[i][j] = zz;

  for (int k0 = 0; k0 < 512; k0 += BK) {
    stage_g(A, (size_t)bm0, k0, lsA, wid, lane);
    stage_g(W, (size_t)bn0, k0, lsB, wid, lane);
    __syncthreads();
#pragma unroll
    for (int ks = 0; ks < 2; ks++) {
      bf16x8 af[4], bfr[4];
#pragma unroll
      for (int t = 0; t < 4; t++) {
        af[t]  = frag_ld(lsA, wm * 64 + t * 16 + (lane & 15), ks, lane);
        bfr[t] = frag_ld(lsB, wn * 64 + t * 16 + (lane & 15), ks, lane);
      }
#pragma unroll
      for (int mt = 0; mt < 4; mt++)
#pragma unroll
        for (int nt = 0; nt < 4; nt++) acc[mt][nt] = mfma16(af[mt], bfr[nt], acc[mt][nt]);
    }
    __syncthreads();
  }
#pragma unroll
  for (int nt = 0; nt < 4; nt++) {
    int j = bn0 + wn * 64 + nt * 16 + (lane & 15);
    float bj = bias[j];
    int which = j >> 9;        // wave-uniform
    int cp = j & 511;
    int h = cp >> 6, d = cp & 63;
    if (which == 2) {
#pragma unroll
      for (int mt = 0; mt < 4; mt++) {
        int m = bm0 + wm * 64 + mt * 16 + 4 * (lane >> 4);
        int b = m >> 12, n = m & 4095;
        u16x4 pk;
#pragma unroll
        for (int r = 0; r < 4; r++) pk[r] = f2bf(acc[mt][nt][r] + bj);
        *reinterpret_cast<u16x4*>(&vt[((size_t)((b * NH + h) * HD + d)) * NTOK + n]) = pk;
      }
    } else {
      unsigned short* dst = (which == 0) ? qb : kb;
      float sc = (which == 0) ? QSC : 1.0f;
#pragma unroll
      for (int mt = 0; mt < 4; mt++) {
#pragma unroll
        for (int r = 0; r < 4; r++) {
          int m = bm0 + wm * 64 + mt * 16 + 4 * (lane >> 4) + r;
          int b = m >> 12, n = m & 4095;
          dst[(((size_t)(b * NH + h) * NTOK + n) << 6) + d] = f2bf((acc[mt][nt][r] + bj) * sc);
        }
      }
    }
  }
}

// ---------------- kernel 4: flash attention (r12 best-measured variant) ----------------
// Block = 4 waves, 64 q/block, 1024 blocks (4/CU). Wave w: q-pair (w>>1, 32 q)
// x kv-half (w&1). Shared tile stream (32KB dbuf). sigma in-register P (no
// P-LDS round-trip); no-max softmax (exp2 via q pre-scale); l via ones-MFMA;
// kv-half partials additive -> in-block LDS merge; bijective XCD swizzle.
#define KVB 64
#define NT  (NTOK / KVB)   // 64

static __device__ __forceinline__ void stage_kv(const unsigned short* __restrict__ Kp,
                                                const unsigned short* __restrict__ Vp,
                                                unsigned short* __restrict__ lk,
                                                unsigned short* __restrict__ lv,
                                                int kv0, int wid, int lane) {
  int sub = lane >> 3;        // row within 8-row group
  int c7  = lane & 7;         // dest chunk
#pragma unroll
  for (int i = 0; i < 2; i++) {
    int rbase = 16 * wid + 8 * i;
    int row = rbase + sub;
    int fk = (sub & 3) | (i << 2);          // f(row) for K (sigma key)
    gload_lds16(&Kp[((size_t)(kv0 + row) << 6) + ((c7 ^ fk) << 3)], &lk[rbase << 6]);
    gload_lds16(&Vp[(size_t)row * NTOK + kv0 + ((c7 ^ sub) << 3)], &lv[rbase << 6]);
  }
}

static __device__ __forceinline__ void attn_tile(const unsigned short* __restrict__ lk,
                                                 const unsigned short* __restrict__ lv,
                                                 int half,
                                                 const bf16x8 qf[2][2],
                                                 f32x4* oacc0, f32x4* oacc1,
                                                 f32x4& lacc0, f32x4& lacc1,
                                                 bf16x8 onesf, int g, int lr) {
  f32x4 zz = {0.f, 0.f, 0.f, 0.f};
  int l7 = lr & 7;
  int tbase = 32 * half + 8 * (lr >> 2) + (lr & 3);
  int kc0 = (g ^ l7) << 3;
  int kc1 = ((4 + g) ^ l7) << 3;
  // K fragments (sigma row order), kv-half of the tile
  bf16x8 kf[2][2];
#pragma unroll
  for (int ct = 0; ct < 2; ct++) {
    int t = tbase + 4 * ct;
    kf[ct][0] = *reinterpret_cast<const bf16x8*>(&lk[(t << 6) + kc0]);
    kf[ct][1] = *reinterpret_cast<const bf16x8*>(&lk[(t << 6) + kc1]);
  }
  f32x4 s0[2], s1[2];
#pragma unroll
  for (int ct = 0; ct < 2; ct++) {
    s0[ct] = mfma16(kf[ct][0], qf[0][0], zz);
    s0[ct] = mfma16(kf[ct][1], qf[0][1], s0[ct]);
    s1[ct] = mfma16(kf[ct][0], qf[1][0], zz);
    s1[ct] = mfma16(kf[ct][1], qf[1][1], s1[ct]);
  }
  // V fragments for this kv-half (issue early; hides under softmax)
  bf16x8 vf[4];
  int vc = (((half << 2) + g) ^ l7) << 3;
#pragma unroll
  for (int dt = 0; dt < 4; dt++)
    vf[dt] = *reinterpret_cast<const bf16x8*>(&lv[((dt * 16 + lr) << 6) + vc]);
  // softmax: exp2 then pack straight into PV A-fragments (in-register)
#pragma unroll
  for (int ct = 0; ct < 2; ct++) {
#pragma unroll
    for (int r = 0; r < 4; r++) {
      s0[ct][r] = __builtin_exp2f(s0[ct][r]);
      s1[ct][r] = __builtin_exp2f(s1[ct][r]);
    }
  }
  unsigned int w0[2][2], w1[2][2];
#pragma unroll
  for (int ct = 0; ct < 2; ct++) {
    asm("v_cvt_pk_bf16_f32 %0, %1, %2" : "=v"(w0[ct][0]) : "v"(s0[ct][0]), "v"(s0[ct][1]));
    asm("v_cvt_pk_bf16_f32 %0, %1, %2" : "=v"(w0[ct][1]) : "v"(s0[ct][2]), "v"(s0[ct][3]));
    asm("v_cvt_pk_bf16_f32 %0, %1, %2" : "=v"(w1[ct][0]) : "v"(s1[ct][0]), "v"(s1[ct][1]));
    asm("v_cvt_pk_bf16_f32 %0, %1, %2" : "=v"(w1[ct][1]) : "v"(s1[ct][2]), "v"(s1[ct][3]));
  }
  union U { unsigned int w[4]; bf16x8 v; };
  U a0, b0;
  a0.w[0] = w0[0][0]; a0.w[1] = w0[0][1]; a0.w[2] = w0[1][0]; a0.w[3] = w0[1][1]; // k=8g..8g+7
  b0.w[0] = w1[0][0]; b0.w[1] = w1[0][1]; b0.w[2] = w1[1][0]; b0.w[3] = w1[1][1];
#pragma unroll
  for (int dt = 0; dt < 4; dt++) {
    oacc0[dt] = mfma16(a0.v, vf[dt], oacc0[dt]);
    oacc1[dt] = mfma16(b0.v, vf[dt], oacc1[dt]);
  }
  lacc0 = mfma16(a0.v, onesf, lacc0);
  lacc1 = mfma16(b0.v, onesf, lacc1);
}

__global__ __launch_bounds__(256, 4) void k_attn(const unsigned short* __restrict__ Q,
                                                 const unsigned short* __restrict__ K,
                                                 const unsigned short* __restrict__ Vt,
                                                 unsigned short* __restrict__ O) {
  __shared__ unsigned short lsK[2][KVB * 64];      // 8KB each (merge O reuses)
  __shared__ unsigned short lsV[2][64 * KVB];      // 8KB each (merge l reuses)
  // bijective XCD swizzle: 128 consecutive vv (= 2 bh) per XCD -> K/V L2-resident
  int gid = blockIdx.x;                            // 1024 blocks
  int vv  = (gid & 7) * 128 + (gid >> 3);
  int bh  = vv >> 6;
  int tid = threadIdx.x, lane = tid & 63, wid = tid >> 6;
  int pair = wid >> 1, half = wid & 1;
  int g = lane >> 4, lr = lane & 15;
  int qw = (vv & 63) * 64 + pair * 32;
  const unsigned short* Qp = Q + (size_t)bh * NTOK * HD;
  const unsigned short* Kp = K + (size_t)bh * NTOK * HD;
  const unsigned short* Vp = Vt + (size_t)bh * HD * NTOK;
  unsigned short* K0 = &lsK[0][0]; unsigned short* K1 = &lsK[1][0];
  unsigned short* V0 = &lsV[0][0]; unsigned short* V1 = &lsV[1][0];

  union { unsigned short u[8]; bf16x8 v; } ou;
#pragma unroll
  for (int i = 0; i < 8; i++) ou.u[i] = 0x3F80;   // bf16 1.0
  bf16x8 onesf = ou.v;

  bf16x8 qf[2][2];
#pragma unroll
  for (int sq = 0; sq < 2; sq++)
#pragma unroll
    for (int ks = 0; ks < 2; ks++)
      qf[sq][ks] = *reinterpret_cast<const bf16x8*>(
          &Qp[(size_t)(qw + sq * 16 + lr) * HD + ks * 32 + 8 * g]);

  f32x4 zz = {0.f, 0.f, 0.f, 0.f};
  f32x4 oacc0[4] = {zz, zz, zz, zz};
  f32x4 oacc1[4] = {zz, zz, zz, zz};
  f32x4 lacc0 = zz, lacc1 = zz;

  stage_kv(Kp, Vp, K0, V0, 0, wid, lane);
  __syncthreads();

  for (int t = 0; t < NT; t += 2) {
    stage_kv(Kp, Vp, K1, V1, (t + 1) * KVB, wid, lane);
    attn_tile(K0, V0, half, qf, oacc0, oacc1, lacc0, lacc1, onesf, g, lr);
    __syncthreads();
    if (t + 2 < NT) stage_kv(Kp, Vp, K0, V0, (t + 2) * KVB, wid, lane);
    attn_tile(K1, V1, half, qf, oacc0, oacc1, lacc0, lacc1, onesf, g, lr);
    __syncthreads();
  }
  // ---- in-block merge of kv-half partials (additive: no-max softmax) ----
  float* mO = (float*)&lsK[0][0];    // [pair][32 q][64 d] f32 = 16KB
  float* mL = (float*)&lsV[0][0];    // [pair][32 q] f32
  if (half) {
#pragma unroll
    for (int sq = 0; sq < 2; sq++) {
      f32x4* oacc = sq ? oacc1 : oacc0;
      f32x4  lacc = sq ? lacc1 : lacc0;
#pragma unroll
      for (int r = 0; r < 4; r++) {
        int q = pair * 32 + sq * 16 + 4 * g + r;
#pragma unroll
        for (int dt = 0; dt < 4; dt++) mO[(q << 6) + dt * 16 + lr] = oacc[dt][r];
        if (lr == 0) mL[q] = lacc[r];
      }
    }
  }
  __syncthreads();
  if (!half) {
    int b2 = bh >> 3, h = bh & 7;
#pragma unroll
    for (int sq = 0; sq < 2; sq++) {
      f32x4* oacc = sq ? oacc1 : oacc0;
      f32x4  lacc = sq ? lacc1 : lacc0;
#pragma unroll
      for (int r = 0; r < 4; r++) {
        int q = pair * 32 + sq * 16 + 4 * g + r;
        float inv = 1.0f / (lacc[r] + mL[q]);
        int n = qw + sq * 16 + 4 * g + r;
#pragma unroll
        for (int dt = 0; dt < 4; dt++) {
          int d = dt * 16 + lr;
          float o = oacc[dt][r] + mO[(q << 6) + dt * 16 + lr];
          O[((size_t)(b2 * NTOK + n)) * CH + h * HD + d] = f2bf(o * inv);
        }
      }
    }
  }
}

// ---------------- kernel 5: out-proj GEMM + bias + residual -> res bf16 ----------------
// BM=64 (512 blocks, 2/CU), BN=128
__global__ __launch_bounds__(256) void k_gemm_out(const unsigned short* __restrict__ A,
                                                  const unsigned short* __restrict__ W,
                                                  const float* __restrict__ bias,
                                                  const unsigned short* __restrict__ tokB,
                                                  unsigned short* __restrict__ res) {
  __shared__ unsigned short lsA[64 * BK];
  __shared__ unsigned short lsB[128 * BK];
  int bm0 = blockIdx.x * 64;
  int bn0 = blockIdx.y * 128;
  int tid = threadIdx.x, lane = tid & 63, wid = tid >> 6;
  int wm = wid >> 1, wn = wid & 1;

  f32x4 acc[2][4];
  f32x4 zz = {0.f, 0.f, 0.f, 0.f};
#pragma unroll
  for (int i = 0; i < 2; i++)
#pragma unroll
    for (int j = 0; j < 4; j++) acc[i][j] = zz;

  for (int k0 = 0; k0 < 512; k0 += BK) {
    stage_g64(A, (size_t)bm0, k0, lsA, wid, lane);
    stage_g(W, (size_t)bn0, k0, lsB, wid, lane);
    __syncthreads();
#pragma unroll
    for (int ks = 0; ks < 2; ks++) {
      bf16x8 af[2], bfr[4];
#pragma unroll
      for (int t = 0; t < 2; t++)
        af[t] = frag_ld(lsA, wm * 32 + t * 16 + (lane & 15), ks, lane);
#pragma unroll
      for (int t = 0; t < 4; t++)
        bfr[t] = frag_ld(lsB, wn * 64 + t * 16 + (lane & 15), ks, lane);
#pragma unroll
      for (int mt = 0; mt < 2; mt++)
#pragma unroll
        for (int nt = 0; nt < 4; nt++) acc[mt][nt] = mfma16(af[mt], bfr[nt], acc[mt][nt]);
    }
    __syncthreads();
  }
#pragma unroll
  for (int nt = 0; nt < 4; nt++) {
    int j = bn0 + wn * 64 + nt * 16 + (lane & 15);
    float bj = bias[j];
#pragma unroll
    for (int mt = 0; mt < 2; mt++) {
#pragma unroll
      for (int r = 0; r < 4; r++) {
        int m = bm0 + wm * 32 + mt * 16 + 4 * (lane >> 4) + r;
        size_t idx = (size_t)m * CH + j;
        float tk = __uint_as_float((unsigned int)tokB[idx] << 16);
        res[idx] = f2bf(acc[mt][nt][r] + bj + tk);
      }
    }
  }
}

// ---------------- kernel 6: LayerNorm over C (bf16 res) + transposed write ----------------
// 256 blocks x 32 rows (was 128 x 64: only 0.5 blocks/CU)
__global__ __launch_bounds__(256) void k_ln(const unsigned short* __restrict__ res,
                                            const float* __restrict__ g,
                                            const float* __restrict__ bb,
                                            float* __restrict__ y) {
  __shared__ float smean[32], srstd[32];
  int m0 = blockIdx.x * 32;
  int tid = threadIdx.x, lane = tid & 63, wid = tid >> 6;
  for (int t = 0; t < 8; t++) {
    int idx = wid * 8 + t;
    uint4 v = *reinterpret_cast<const uint4*>(&res[(size_t)(m0 + idx) * CH + lane * 8]);
    unsigned int wv[4] = {v.x, v.y, v.z, v.w};
    float s = 0.f, ss = 0.f;
#pragma unroll
    for (int j = 0; j < 4; j++) {
      float lo = __uint_as_float(wv[j] << 16);
      float hi = __uint_as_float(wv[j] & 0xFFFF0000u);
      s += lo + hi; ss += lo * lo + hi * hi;
    }
#pragma unroll
    for (int off = 1; off < 64; off <<= 1) {
      s += __shfl_xor(s, off);
      ss += __shfl_xor(ss, off);
    }
    if (lane == 0) {
      float mean = s * (1.0f / CH);
      float var = ss * (1.0f / CH) - mean * mean;
      smean[idx] = mean;
      srstd[idx] = rsqrtf(var + 1e-5f);
    }
  }
  __syncthreads();
  int b = m0 >> 12, n0 = m0 & 4095;
  int tn = tid & 31;
  int cq = tid >> 5;     // 0..7
  float mn = smean[tn], rs = srstd[tn];
  const unsigned short* rrow = res + (size_t)(m0 + tn) * CH;
  float* yb = y + ((size_t)b * CH) * NTOK + n0 + tn;
#pragma unroll
  for (int i = 0; i < 8; i++) {
    int c = cq * 64 + i * 8;
    uint4 v = *reinterpret_cast<const uint4*>(&rrow[c]);
    unsigned int wv[4] = {v.x, v.y, v.z, v.w};
    float4 ga = *reinterpret_cast<const float4*>(&g[c]);
    float4 gb = *reinterpret_cast<const float4*>(&g[c + 4]);
    float4 ba = *reinterpret_cast<const float4*>(&bb[c]);
    float4 b4 = *reinterpret_cast<const float4*>(&bb[c + 4]);
    float gg[8] = {ga.x, ga.y, ga.z, ga.w, gb.x, gb.y, gb.z, gb.w};
    float bv[8] = {ba.x, ba.y, ba.z, ba.w, b4.x, b4.y, b4.z, b4.w};
#pragma unroll
    for (int j = 0; j < 4; j++) {
      float lo = __uint_as_float(wv[j] << 16);
      float hi = __uint_as_float(wv[j] & 0xFFFF0000u);
      yb[(size_t)(c + 2 * j) * NTOK]     = (lo - mn) * rs * gg[2 * j]     + bv[2 * j];
      yb[(size_t)(c + 2 * j + 1) * NTOK] = (hi - mn) * rs * gg[2 * j + 1] + bv[2 * j + 1];
    }
  }
}

// ---------------- launch ----------------
extern "C" void kernel_launch(void* const* d_in, const int* in_sizes, int n_in,
                              void* d_out, int out_size, void* d_ws, size_t ws_size,
                              hipStream_t stream) {
  const float* x    = (const float*)d_in[0];
  const float* qkvw = (const float*)d_in[1];
  const float* qkvb = (const float*)d_in[2];
  const float* outw = (const float*)d_in[3];
  const float* outb = (const float*)d_in[4];
  const float* lng  = (const float*)d_in[5];
  const float* lnb  = (const float*)d_in[6];
  float* y = (float*)d_out;

  const size_t NC = (size_t)MTOT * CH;   // 4.2M elements
  char* ws = (char*)d_ws;
  size_t off = 0;
  auto nxt = [&](size_t bytes) -> void* {
    void* p = ws + off;
    off += (bytes + 255) & ~(size_t)255;
    return p;
  };
  unsigned short* tokB = (unsigned short*)nxt(NC * 2);
  unsigned short* wqkv = (unsigned short*)nxt((size_t)3 * CH * CH * 2);
  unsigned short* wout = (unsigned short*)nxt((size_t)CH * CH * 2);
  unsigned short* qb   = (unsigned short*)nxt(NC * 2);
  unsigned short* kb   = (unsigned short*)nxt(NC * 2);
  unsigned short* vt   = (unsigned short*)nxt(NC * 2);
  unsigned short* ao   = (unsigned short*)nxt(NC * 2);
  unsigned short* resb = (unsigned short*)nxt(NC * 2);
  if (off > ws_size) return;

  k_pre<<<8192, 256, 0, stream>>>(x, qkvw, outw, tokB, wqkv, wout);
  k_gemm_qkv<<<dim3(MTOT / 128, (3 * CH) / 128), 256, 0, stream>>>(tokB, wqkv, qkvb, qb, kb, vt);
  k_attn<<<1024, 256, 0, stream>>>(qb, kb, vt, ao);
  k_gemm_out<<<dim3(MTOT / 64, CH / 128), 256, 0, stream>>>(ao, wout, outb, tokB, resb);
  k_ln<<<MTOT / 32, 256, 0, stream>>>(resb, lng, lnb, y);
}